// Round 11
// baseline (287.944 us; speedup 1.0000x reference)
//
#include <hip/hip_runtime.h>
#include <hip/hip_fp16.h>

#define BB 4
#define NN 120000
#define FEAT 128
#define HH 128
#define WW 128
#define NPTS (BB*NN)
#define HW (HH*WW)

// ---- ws layout (4-byte element offsets) ----
#define OW1    0         // f32[256]  [o=64][i=4]
#define OB1    256       // f32[64]
#define OW2P   320       // u32[4096] packed half2 [r=32][o=128] (fallback)
#define OB2    4416      // f32[128]
#define OW3P   4544      // u32[8192] chunk layout (fallback)
#define OB3    12736     // f32[128]
#define OW3F   12864     // u32[8192] W3 A-frag, sigma-permuted K
#define OW2F   21056     // u32[4096] W2 A-frag-linear
#define OB2L   25152     // f32[2048] bias2 lane-broadcast float4 [mt][lane]
#define OB3L   27200     // f32[2048] bias3 lane-broadcast float4 [mt][lane]
#define OCNT   29248     // i32[65536]
#define OOFF   94784     // i32[65536]
#define ONV    160320    // i32[1] (padded to 64)
#define OCELLS 160384    // i32[NPTS]
#define OSIDX  640384    // i32[NPTS]
#define OSCELL 1120384   // i32[NPTS]
#define OFEATS 1600384   // u32[NPTS*64] fp16 feats [slot][128]
#define OBEV   1600384   // fallback bev region (aliases OFEATS)
#define BEV_ELEMS (BB*HW*FEAT)

#if defined(__has_builtin)
#if __has_builtin(__builtin_amdgcn_fdot2)
#define HAS_FDOT2 1
#endif
#if __has_builtin(__builtin_amdgcn_cvt_pkrtz)
#define HAS_PKRTZ 1
#endif
#endif

typedef _Float16 hv2 __attribute__((ext_vector_type(2)));
typedef __fp16   pkv2 __attribute__((ext_vector_type(2)));   // cvt_pkrtz return type
typedef _Float16 f16x8 __attribute__((ext_vector_type(8)));
typedef float    f32x4 __attribute__((ext_vector_type(4)));
typedef float    fv16  __attribute__((ext_vector_type(16)));

__device__ __forceinline__ unsigned pk2(float a, float b) {
    __half2 h = __floats2half2_rn(a, b);
    return __builtin_bit_cast(unsigned, h);
}

// single-instruction f32x2 -> packed fp16 (v_cvt_pkrtz_f16_f32)
__device__ __forceinline__ unsigned pkz(float a, float b) {
#ifdef HAS_PKRTZ
    pkv2 h = __builtin_amdgcn_cvt_pkrtz(a, b);
    return __builtin_bit_cast(unsigned, h);
#else
    return pk2(a, b);
#endif
}

__device__ __forceinline__ float dot2(unsigned a, unsigned b, float c) {
#ifdef HAS_FDOT2
    return __builtin_amdgcn_fdot2(__builtin_bit_cast(hv2, a),
                                  __builtin_bit_cast(hv2, b), c, false);
#else
    __half2 ah = __builtin_bit_cast(__half2, a), bh = __builtin_bit_cast(__half2, b);
    c = fmaf(__low2float(ah), __low2float(bh), c);
    return fmaf(__high2float(ah), __high2float(bh), c);
#endif
}

// post-ReLU fp16 (>=0) orders as unsigned halfwords
__device__ __forceinline__ unsigned hmax2u(unsigned a, unsigned b) {
    unsigned al = a & 0xFFFFu, bl = b & 0xFFFFu;
    unsigned ah = a & 0xFFFF0000u, bh = b & 0xFFFF0000u;
    unsigned lo = (al > bl) ? al : bl;
    unsigned hi = (ah > bh) ? ah : bh;
    return lo | hi;
}

__device__ __forceinline__ f32x4 mfma16(uint4 a, uint4 b, f32x4 c) {
    return __builtin_amdgcn_mfma_f32_16x16x32_f16(
        __builtin_bit_cast(f16x8, a), __builtin_bit_cast(f16x8, b), c, 0, 0, 0);
}

// ---------------- weight folding + fp16 packing (+ cnt zeroing) ----------------
__global__ void fold_weights_k(
    const float* __restrict__ W1, const float* __restrict__ b1,
    const float* __restrict__ g1, const float* __restrict__ be1,
    const float* __restrict__ m1, const float* __restrict__ v1,
    const float* __restrict__ W2, const float* __restrict__ b2,
    const float* __restrict__ g2, const float* __restrict__ be2,
    const float* __restrict__ m2, const float* __restrict__ v2,
    const float* __restrict__ W3, const float* __restrict__ b3,
    const float* __restrict__ g3, const float* __restrict__ be3,
    const float* __restrict__ m3, const float* __restrict__ v3,
    float* __restrict__ wf)
{
    unsigned* wu = (unsigned*)wf;
    int idx = blockIdx.x * 256 + threadIdx.x;
    const float EPSV = 1e-5f;
    if (idx < 256) {
        int o = idx >> 2;
        float s = g1[o] * rsqrtf(v1[o] + EPSV);
        wf[OW1 + idx] = W1[idx] * s;
    } else if (idx < 320) {
        int o = idx - 256;
        float s = g1[o] * rsqrtf(v1[o] + EPSV);
        wf[idx] = (b1[o] - m1[o]) * s + be1[o];
    } else if (idx < 4416) {
        int j = idx - OW2P;
        int r = j >> 7, o = j & 127;
        float s = g2[o] * rsqrtf(v2[o] + EPSV);
        wu[idx] = pk2(W2[o * 64 + 2 * r] * s, W2[o * 64 + 2 * r + 1] * s);
    } else if (idx < 4544) {
        int o = idx - OB2;
        float s = g2[o] * rsqrtf(v2[o] + EPSV);
        wf[idx] = (b2[o] - m2[o]) * s + be2[o];
    } else if (idx < 12736) {               // chunk layout (fallback path)
        int j = idx - OW3P;
        int ch = j >> 9, rem = j & 511;
        int r = rem >> 3, jj = rem & 7;
        int o = ch * 8 + jj;
        float s = g3[o] * rsqrtf(v3[o] + EPSV);
        wu[idx] = pk2(W3[o * 128 + 2 * r] * s, W3[o * 128 + 2 * r + 1] * s);
    } else if (idx < 12864) {
        int o = idx - OB3;
        float s = g3[o] * rsqrtf(v3[o] + EPSV);
        wf[idx] = (b3[o] - m3[o]) * s + be3[o];
    } else if (idx < 21056) {
        // W3 A-frag with sigma-permuted K: tile = mt3*4+kt; lane l:
        // m3 = (tile>>2)*16 + (l&15); K-pos kappa = kt*32 + (l>>4)*8 + j.
        // sigma: logical h2 feature f(j) = ((j>>2)*4 + kt)*16 + (l>>4)*4 + (j&3)
        // (makes L2-output registers land exactly where L3's B-operand needs them)
        int u = idx - OW3F;
        int tile = u >> 8, w = u & 255;
        int l = w >> 2, qq = w & 3;
        int q = l >> 4;
        int m3 = (tile >> 2) * 16 + (l & 15);
        int kt = tile & 3;
        int j0 = 2 * qq, j1 = 2 * qq + 1;
        int f0 = ((j0 >> 2) * 4 + kt) * 16 + q * 4 + (j0 & 3);
        int f1 = ((j1 >> 2) * 4 + kt) * 16 + q * 4 + (j1 & 3);
        float s = g3[m3] * rsqrtf(v3[m3] + EPSV);
        wu[idx] = pk2(W3[m3 * 128 + f0] * s, W3[m3 * 128 + f1] * s);
    } else if (idx < 25152) {
        // W2 frag-linear: tile = mt*2+kt; lane l: m = (tile>>1)*16+(l&15),
        // k = (tile&1)*32 + (l>>4)*8 + j  (true h1 feature order)
        int u = idx - OW2F;
        int tile = u >> 8, w = u & 255;
        int l = w >> 2, q = w & 3;
        int n = (tile >> 1) * 16 + (l & 15);
        int k = (tile & 1) * 32 + ((l >> 4) << 3) + 2 * q;
        float s = g2[n] * rsqrtf(v2[n] + EPSV);
        wu[idx] = pk2(W2[n * 64 + k] * s, W2[n * 64 + k + 1] * s);
    } else if (idx < 27200) {
        // bias2 lane-broadcast: [mt][lane] float4 over rr; feature mt*16+q*4+rr
        int f = idx - OB2L;
        int mt = f >> 8, l = (f >> 2) & 63, rr = f & 3;
        int o = mt * 16 + (l >> 4) * 4 + rr;
        float s = g2[o] * rsqrtf(v2[o] + EPSV);
        wf[idx] = (b2[o] - m2[o]) * s + be2[o];
    } else if (idx < 29248) {
        int f = idx - OB3L;
        int mt = f >> 8, l = (f >> 2) & 63, rr = f & 3;
        int o = mt * 16 + (l >> 4) * 4 + rr;
        float s = g3[o] * rsqrtf(v3[o] + EPSV);
        wf[idx] = (b3[o] - m3[o]) * s + be3[o];
    } else if (idx < 29248 + 65536) {
        ((int*)wf)[OCNT + idx - 29248] = 0;   // zero histogram
    }
}

// ---------------- sort-by-cell passes ----------------
__global__ __launch_bounds__(256)
void cells_hist_k(const float4* __restrict__ pts, int* __restrict__ cells,
                  int* __restrict__ cnt)
{
    int tid = blockIdx.x * 256 + threadIdx.x;
    float4 p = pts[tid];
    float xn = (p.x - (-50.0f)) / (50.0f - (-50.0f));
    float yn = (p.y - (-50.0f)) / (50.0f - (-50.0f));
    bool valid = (xn >= 0.0f) && (xn <= 1.0f) && (yn >= 0.0f) && (yn <= 1.0f);
    int gx = min(max((int)(xn * 127.0f), 0), 127);
    int gy = min(max((int)(yn * 127.0f), 0), 127);
    int b = tid / NN;
    int cell = valid ? (b * HW + gy * WW + gx) : -1;
    cells[tid] = cell;
    if (valid) atomicAdd(&cnt[cell], 1);
}

__global__ __launch_bounds__(1024)
void scan_k(const int* __restrict__ cnt, int* __restrict__ off, int* __restrict__ nvp)
{
    __shared__ int wsum[16];
    int t = threadIdx.x;
    int lane = t & 63, w = t >> 6;
    int base = t * 64;
    int s = 0;
#pragma unroll 8
    for (int j = 0; j < 64; ++j) s += cnt[base + j];
    int v = s;
#pragma unroll
    for (int d = 1; d < 64; d <<= 1) {
        int u = __shfl_up(v, d);
        if (lane >= d) v += u;
    }
    if (lane == 63) wsum[w] = v;
    __syncthreads();
    if (t == 0) {
        int r = 0;
#pragma unroll
        for (int k = 0; k < 16; ++k) { int x = wsum[k]; wsum[k] = r; r += x; }
        nvp[0] = r;
    }
    __syncthreads();
    int excl = (v - s) + wsum[w];
    int r = excl;
#pragma unroll 8
    for (int j = 0; j < 64; ++j) { off[base + j] = r; r += cnt[base + j]; }
}

__global__ __launch_bounds__(256)
void scatter_idx_k(const int* __restrict__ cells, int* __restrict__ off,
                   int* __restrict__ sidx, int* __restrict__ scell)
{
    int tid = blockIdx.x * 256 + threadIdx.x;
    int c = cells[tid];
    if (c >= 0) {
        int pos = atomicAdd(&off[c], 1);
        sidx[pos] = tid;
        scell[pos] = c;
    }
}

// ---------------- fused MLP: weights=A, points=B; ZERO LDS, zero shuffles ----
// Wave = 16 points. L1 computed in B-frag order; L2 output (rows=features)
// lands, via the sigma-permuted W3A table, exactly as L3's B-frags: pure
// register renaming between layers. Bias folded into MFMA C-init.
__global__ __launch_bounds__(256)
void fused_mlp_k(const float4* __restrict__ pts, const float* __restrict__ wf,
                 const int* __restrict__ sidx, const int* __restrict__ nvp,
                 uint2* __restrict__ feats2)
{
    const unsigned* wu = (const unsigned*)wf;
    const uint4* A2 = (const uint4*)(wu + OW2F);
    const uint4* A3 = (const uint4*)(wu + OW3F);
    const float4* B2L = (const float4*)(wf + OB2L);
    const float4* B3L = (const float4*)(wf + OB3L);
    const int tid = threadIdx.x, wv = tid >> 6, l = tid & 63;
    const int nv = nvp[0];
    const int M0 = (blockIdx.x * 4 + wv) * 16;
    if (M0 >= nv) return;                       // wave-uniform
    const int l15 = l & 15, q = l >> 4;

    const int slot = M0 + l15;
    const int pidx = (slot < nv) ? sidx[slot] : 0;
    float4 p = pts[pidx];

    // ---- L1 directly in B-frag order: h1 feature k = kt*32 + q*8 + j
    uint4 a2[2];
#pragma unroll
    for (int kt = 0; kt < 2; ++kt) {
        unsigned w4[4];
#pragma unroll
        for (int t = 0; t < 4; ++t) {
            int f = kt * 32 + q * 8 + 2 * t;
            const float* wa = wf + OW1 + f * 4;
            float a = wf[OB1 + f], b = wf[OB1 + f + 1];
            a = fmaf(wa[0], p.x, a); a = fmaf(wa[1], p.y, a);
            a = fmaf(wa[2], p.z, a); a = fmaf(wa[3], p.w, a);
            b = fmaf(wa[4], p.x, b); b = fmaf(wa[5], p.y, b);
            b = fmaf(wa[6], p.z, b); b = fmaf(wa[7], p.w, b);
            w4[t] = pkz(fmaxf(a, 0.f), fmaxf(b, 0.f));
        }
        uint4 v; v.x = w4[0]; v.y = w4[1]; v.z = w4[2]; v.w = w4[3];
        a2[kt] = v;
    }

    // ---- L2: D[feature][point]; lane holds point l15, features mt*16+q*4+rr
    unsigned pk[8][2];
#pragma unroll
    for (int mt = 0; mt < 8; ++mt) {
        float4 bv = B2L[mt * 64 + l];
        f32x4 acc = {bv.x, bv.y, bv.z, bv.w};   // bias as C-init
        acc = mfma16(A2[(mt * 2 + 0) * 64 + l], a2[0], acc);
        acc = mfma16(A2[(mt * 2 + 1) * 64 + l], a2[1], acc);
        pk[mt][0] = pkz(fmaxf(acc[0], 0.f), fmaxf(acc[1], 0.f));
        pk[mt][1] = pkz(fmaxf(acc[2], 0.f), fmaxf(acc[3], 0.f));
    }

    // ---- L2 -> L3 operand hand-off: pure register renaming (sigma-permuted W3A)
    uint4 b3[4];
#pragma unroll
    for (int kt = 0; kt < 4; ++kt) {
        uint4 v;
        v.x = pk[kt][0];     v.y = pk[kt][1];
        v.z = pk[kt + 4][0]; v.w = pk[kt + 4][1];
        b3[kt] = v;
    }

    // ---- L3: true output feature = mt*16+q*4+rr; direct dense uint2 stores
#pragma unroll
    for (int mt = 0; mt < 8; ++mt) {
        float4 bv = B3L[mt * 64 + l];
        f32x4 acc = {bv.x, bv.y, bv.z, bv.w};
#pragma unroll
        for (int kt = 0; kt < 4; ++kt)
            acc = mfma16(A3[(mt * 4 + kt) * 64 + l], b3[kt], acc);
        uint2 o;
        o.x = pkz(fmaxf(acc[0], 0.f), fmaxf(acc[1], 0.f));
        o.y = pkz(fmaxf(acc[2], 0.f), fmaxf(acc[3], 0.f));
        // u32 idx = slot*64 + mt*8 + q*2 -> 4 q-lanes fill one 32B sector densely
        feats2[(size_t)slot * 32 + mt * 4 + q] = o;
    }
}

// ---------------- per-cell max-reduce, uint4 / 4-row loads ----------------
__global__ __launch_bounds__(256)
void reduce_k(const unsigned* __restrict__ feats, const int* __restrict__ off,
              const int* __restrict__ cnt, float* __restrict__ out)
{
    __shared__ float tile[128][65];
    const int tid = threadIdx.x;
    const int w = tid >> 6, l = tid & 63;
    const int l15 = l & 15, lq = l >> 4;
    const int c0 = blockIdx.x * 64;
    const uint4* f4 = (const uint4*)feats;

#pragma unroll 2
    for (int cc = 0; cc < 16; ++cc) {
        int c = c0 + w * 16 + cc;
        int n = cnt[c];
        int start = off[c] - n;                // off advanced to run end by scatter
        uint4 m = {0u, 0u, 0u, 0u};
        const uint4* fp = f4 + (size_t)(start + lq) * 16 + l15;
#pragma unroll 1
        for (int p = 0; p < n; p += 4) {
            if (p + lq < n) {
                uint4 v = fp[(size_t)p * 16];
                m.x = hmax2u(m.x, v.x); m.y = hmax2u(m.y, v.y);
                m.z = hmax2u(m.z, v.z); m.w = hmax2u(m.w, v.w);
            }
        }
#pragma unroll
        for (int d = 16; d <= 32; d <<= 1) {
            m.x = hmax2u(m.x, (unsigned)__shfl_xor((int)m.x, d));
            m.y = hmax2u(m.y, (unsigned)__shfl_xor((int)m.y, d));
            m.z = hmax2u(m.z, (unsigned)__shfl_xor((int)m.z, d));
            m.w = hmax2u(m.w, (unsigned)__shfl_xor((int)m.w, d));
        }
        if (lq == 0) {
            int f0 = 8 * l15, cl = w * 16 + cc;
            __half2 hx = __builtin_bit_cast(__half2, m.x);
            __half2 hy = __builtin_bit_cast(__half2, m.y);
            __half2 hz = __builtin_bit_cast(__half2, m.z);
            __half2 hw = __builtin_bit_cast(__half2, m.w);
            tile[f0 + 0][cl] = __low2float(hx); tile[f0 + 1][cl] = __high2float(hx);
            tile[f0 + 2][cl] = __low2float(hy); tile[f0 + 3][cl] = __high2float(hy);
            tile[f0 + 4][cl] = __low2float(hz); tile[f0 + 5][cl] = __high2float(hz);
            tile[f0 + 6][cl] = __low2float(hw); tile[f0 + 7][cl] = __high2float(hw);
        }
    }
    __syncthreads();
    const int b = c0 >> 14;
    const int cxy = c0 & (HW - 1);
#pragma unroll 4
    for (int k = 0; k < 32; ++k) {
        int idx = k * 256 + tid;
        int f = idx >> 6, cl = idx & 63;
        out[((size_t)(b * 128 + f)) * HW + cxy + cl] = tile[f][cl];
    }
}

// ---------------- small-ws fallback: sorted+run-merged atomics ----------------
#define DPPMAX(A, D, S) { \
    float _pv = __int_as_float(__builtin_amdgcn_update_dpp( \
        0, __float_as_int(A), 0x110 | (D), 0xF, 0xF, false)); \
    A = (S) ? fmaxf(A, _pv) : A; }

__global__ __launch_bounds__(256)
void mlp_atomic_k(const float4* __restrict__ pts, const float* __restrict__ wf,
                  const int* __restrict__ sidx, const int* __restrict__ scell,
                  const int* __restrict__ nvp, float* __restrict__ bev, int layout)
{
    __shared__ unsigned h1s[32 * 256];
    __shared__ unsigned h2s[64 * 256];
    const unsigned* wu = (const unsigned*)wf;
    const int tid = threadIdx.x;
    const int slot = blockIdx.x * 256 + tid;
    const int nv = nvp[0];
    if ((slot & ~63) >= nv) return;
    const int lane = tid & 63;
    const int l15 = lane & 15;
    const bool live = slot < nv;
    const int cell = live ? scell[slot] : -1;
    const int pidx = live ? sidx[slot] : 0;
    float4 p = pts[pidx];

    int c1 = __shfl_up(cell, 1), c2 = __shfl_up(cell, 2);
    int c4 = __shfl_up(cell, 4), c8 = __shfl_up(cell, 8);
    bool s1 = (l15 >= 1) && (c1 == cell);
    bool s2 = (l15 >= 2) && (c2 == cell);
    bool s4 = (l15 >= 4) && (c4 == cell);
    bool s8 = (l15 >= 8) && (c8 == cell);
    int cn = __shfl_down(cell, 1);
    bool tail = (l15 == 15) || (cn != cell);

#pragma unroll
    for (int i = 0; i < 32; ++i) {
        const float* wa = wf + OW1 + 8 * i;
        float a = wf[OB1 + 2 * i], b = wf[OB1 + 2 * i + 1];
        a = fmaf(wa[0], p.x, a); a = fmaf(wa[1], p.y, a);
        a = fmaf(wa[2], p.z, a); a = fmaf(wa[3], p.w, a);
        b = fmaf(wa[4], p.x, b); b = fmaf(wa[5], p.y, b);
        b = fmaf(wa[6], p.z, b); b = fmaf(wa[7], p.w, b);
        h1s[i * 256 + tid] = pk2(fmaxf(a, 0.0f), fmaxf(b, 0.0f));
    }
#pragma unroll 1
    for (int o0 = 0; o0 < 128; o0 += 16) {
        fv16 acc;
#pragma unroll
        for (int j = 0; j < 16; ++j) acc[j] = wf[OB2 + o0 + j];
#pragma unroll
        for (int r = 0; r < 32; ++r) {
            unsigned h1r = h1s[r * 256 + tid];
            const unsigned* wr = wu + OW2P + r * 128 + o0;
#pragma unroll
            for (int j = 0; j < 16; ++j) acc[j] = dot2(h1r, wr[j], acc[j]);
        }
#pragma unroll
        for (int j = 0; j < 16; j += 2)
            h2s[((o0 + j) >> 1) * 256 + tid] =
                pk2(fmaxf(acc[j], 0.f), fmaxf(acc[j + 1], 0.f));
    }

    int* ob = (int*)bev;
    long base0;
    if (layout == 0) base0 = (long)cell * 128;
    else             base0 = (long)(cell >> 14) * (128 * HW) + (cell & (HW - 1));

#pragma unroll 1
    for (int ch = 0; ch < 16; ++ch) {
        float a0=wf[OB3+ch*8+0], a1=wf[OB3+ch*8+1], a2=wf[OB3+ch*8+2], a3=wf[OB3+ch*8+3];
        float a4=wf[OB3+ch*8+4], a5=wf[OB3+ch*8+5], a6=wf[OB3+ch*8+6], a7=wf[OB3+ch*8+7];
        const unsigned* wq = wu + OW3P + ch * 512;
#pragma unroll
        for (int r = 0; r < 64; ++r) {
            unsigned h2r = h2s[r * 256 + tid];
            a0 = dot2(h2r, wq[r*8+0], a0); a1 = dot2(h2r, wq[r*8+1], a1);
            a2 = dot2(h2r, wq[r*8+2], a2); a3 = dot2(h2r, wq[r*8+3], a3);
            a4 = dot2(h2r, wq[r*8+4], a4); a5 = dot2(h2r, wq[r*8+5], a5);
            a6 = dot2(h2r, wq[r*8+6], a6); a7 = dot2(h2r, wq[r*8+7], a7);
        }
        float av[8] = {a0,a1,a2,a3,a4,a5,a6,a7};
#pragma unroll
        for (int j = 0; j < 8; ++j) {
            float aj = fmaxf(av[j], 0.0f);
            DPPMAX(aj, 1, s1); DPPMAX(aj, 2, s2);
            DPPMAX(aj, 4, s4); DPPMAX(aj, 8, s8);
            av[j] = aj;
        }
        if (tail && cell >= 0) {
            if (layout == 0) {
#pragma unroll
                for (int j = 0; j < 8; ++j)
                    atomicMax(ob + base0 + ch * 8 + j, __float_as_int(av[j]));
            } else {
#pragma unroll
                for (int j = 0; j < 8; ++j)
                    atomicMax(ob + base0 + (long)(ch * 8 + j) * HW, __float_as_int(av[j]));
            }
        }
    }
}

__global__ void transpose_bev_k(const float* __restrict__ bev, float* __restrict__ out)
{
    __shared__ float tile[32][129];
    const int tid = threadIdx.x;
    const int cell0 = blockIdx.x * 32;
#pragma unroll
    for (int k = 0; k < 16; ++k) {
        int idx = k * 256 + tid;
        int c = idx >> 7, f = idx & 127;
        tile[c][f] = bev[(size_t)(cell0 + c) * 128 + f];
    }
    __syncthreads();
    const int b = cell0 >> 14;
    const int cl0 = cell0 & (HW - 1);
#pragma unroll
    for (int k = 0; k < 16; ++k) {
        int idx = k * 256 + tid;
        int f = idx >> 5, c = idx & 31;
        out[(size_t)(b * 128 + f) * HW + cl0 + c] = tile[c][f];
    }
}

extern "C" void kernel_launch(void* const* d_in, const int* in_sizes, int n_in,
                              void* d_out, int out_size, void* d_ws, size_t ws_size,
                              hipStream_t stream)
{
    const float* points = (const float*)d_in[0];
    const float* W1 = (const float*)d_in[1];  const float* b1 = (const float*)d_in[2];
    const float* g1 = (const float*)d_in[3];  const float* be1 = (const float*)d_in[4];
    const float* m1 = (const float*)d_in[5];  const float* v1 = (const float*)d_in[6];
    const float* W2 = (const float*)d_in[7];  const float* b2 = (const float*)d_in[8];
    const float* g2 = (const float*)d_in[9];  const float* be2 = (const float*)d_in[10];
    const float* m2 = (const float*)d_in[11]; const float* v2 = (const float*)d_in[12];
    const float* W3 = (const float*)d_in[13]; const float* b3 = (const float*)d_in[14];
    const float* g3 = (const float*)d_in[15]; const float* be3 = (const float*)d_in[16];
    const float* m3 = (const float*)d_in[17]; const float* v3 = (const float*)d_in[18];

    float* wsf = (float*)d_ws;
    int*   wsi = (int*)d_ws;
    const size_t need_full = ((size_t)OFEATS + (size_t)NPTS * 64) * 4;  // ~129.3 MB
    const size_t need_bev  = ((size_t)OBEV + BEV_ELEMS) * 4;            // ~40 MB

    // fold grid covers 29248 weight/bias items + 65536 cnt zeroes
    fold_weights_k<<<(29248 + 65536 + 255) / 256, 256, 0, stream>>>(
        W1, b1, g1, be1, m1, v1, W2, b2, g2, be2, m2, v2, W3, b3, g3, be3, m3, v3, wsf);

    cells_hist_k<<<NPTS / 256, 256, 0, stream>>>(
        (const float4*)points, wsi + OCELLS, wsi + OCNT);
    scan_k<<<1, 1024, 0, stream>>>(wsi + OCNT, wsi + OOFF, wsi + ONV);
    scatter_idx_k<<<NPTS / 256, 256, 0, stream>>>(
        wsi + OCELLS, wsi + OOFF, wsi + OSIDX, wsi + OSCELL);

    if (ws_size >= need_full) {
        fused_mlp_k<<<NPTS / 64, 256, 0, stream>>>(
            (const float4*)points, wsf, wsi + OSIDX, wsi + ONV,
            (uint2*)(wsi + OFEATS));
        reduce_k<<<BB * HW / 64, 256, 0, stream>>>(
            (const unsigned*)(wsi + OFEATS), wsi + OOFF, wsi + OCNT, (float*)d_out);
    } else if (ws_size >= need_bev) {
        float* bev = wsf + OBEV;
        (void)hipMemsetAsync(bev, 0, (size_t)BEV_ELEMS * sizeof(float), stream);
        mlp_atomic_k<<<NPTS / 256, 256, 0, stream>>>(
            (const float4*)points, wsf, wsi + OSIDX, wsi + OSCELL, wsi + ONV, bev, 0);
        transpose_bev_k<<<HW * BB / 32, 256, 0, stream>>>(bev, (float*)d_out);
    } else {
        (void)hipMemsetAsync(d_out, 0, (size_t)out_size * sizeof(float), stream);
        mlp_atomic_k<<<NPTS / 256, 256, 0, stream>>>(
            (const float4*)points, wsf, wsi + OSIDX, wsi + OSCELL, wsi + ONV,
            (float*)d_out, 1);
    }
}